// Round 1
// baseline (330.147 us; speedup 1.0000x reference)
//
#include <hip/hip_runtime.h>
#include <hip/hip_bf16.h>

typedef __bf16 bf16x8 __attribute__((ext_vector_type(8)));
typedef __bf16 bf16x4 __attribute__((ext_vector_type(4)));
typedef float  f32x4  __attribute__((ext_vector_type(4)));
typedef float  f32x2  __attribute__((ext_vector_type(2)));

#define FP8_MAX 448.0f
#define M 32
#define N 12288
#define K 4096
#define BN 64
#define KSPLIT 4
#define KC (K / KSPLIT)   // 1024
#define BK 64
#define NITER (KC / BK)   // 16
#define PITCH 72          // 64 + 8 pad: 144B rows -> only 2-way LDS bank aliasing (free)

// ---------------- Pass 1: global amax over |W| ----------------
__global__ __launch_bounds__(256) void amax_kernel(const float4* __restrict__ W4,
                                                   unsigned int* __restrict__ amax_bits) {
    const int n4 = (N * K) / 4;           // 12582912 float4
    int idx = blockIdx.x * 256 + threadIdx.x;
    int stride = gridDim.x * 256;
    float m = 0.0f;
    for (int i = idx; i < n4; i += stride) {
        float4 v = W4[i];
        m = fmaxf(m, fabsf(v.x)); m = fmaxf(m, fabsf(v.y));
        m = fmaxf(m, fabsf(v.z)); m = fmaxf(m, fabsf(v.w));
    }
#pragma unroll
    for (int off = 32; off > 0; off >>= 1)
        m = fmaxf(m, __shfl_down(m, off, 64));
    __shared__ float smax[4];
    if ((threadIdx.x & 63) == 0) smax[threadIdx.x >> 6] = m;
    __syncthreads();
    if (threadIdx.x == 0) {
        float bm = fmaxf(fmaxf(smax[0], smax[1]), fmaxf(smax[2], smax[3]));
        // all values >= 0: uint bit pattern order == float order
        atomicMax(amax_bits, __float_as_uint(bm));
    }
}

// quantize 4 fp32 weights -> fp8 e4m3fn (HW RNE) -> dequant -> bf16
__device__ inline bf16x4 quant4(const float4 w, float scale, float recip) {
    float x0 = fminf(fmaxf(w.x * scale, -FP8_MAX), FP8_MAX);
    float x1 = fminf(fmaxf(w.y * scale, -FP8_MAX), FP8_MAX);
    float x2 = fminf(fmaxf(w.z * scale, -FP8_MAX), FP8_MAX);
    float x3 = fminf(fmaxf(w.w * scale, -FP8_MAX), FP8_MAX);
    int p01 = __builtin_amdgcn_cvt_pk_fp8_f32(x0, x1, 0, false);
    int p23 = __builtin_amdgcn_cvt_pk_fp8_f32(x2, x3, 0, false);
    f32x2 d01 = __builtin_amdgcn_cvt_pk_f32_fp8(p01, false);
    f32x2 d23 = __builtin_amdgcn_cvt_pk_f32_fp8(p23, false);
    bf16x4 r;
    r.x = (__bf16)(d01.x * recip);
    r.y = (__bf16)(d01.y * recip);
    r.z = (__bf16)(d23.x * recip);
    r.w = (__bf16)(d23.y * recip);
    return r;
}

// ---------------- Pass 2: fused quantize + GEMM ----------------
// grid: (N/BN = 192, KSPLIT = 4), block: 256 (4 waves)
// wave w handles 16 columns [n0 + 16w, +16), both 16-row m-tiles.
__global__ __launch_bounds__(256) void fused_gemm(const float* __restrict__ A,
                                                  const float* __restrict__ W,
                                                  const float* __restrict__ bias,
                                                  const unsigned int* __restrict__ amax_bits,
                                                  float* __restrict__ C) {
    const int n0 = blockIdx.x * BN;
    const int kbase0 = blockIdx.y * KC;
    float amax = fmaxf(__uint_as_float(*amax_bits), 1e-12f);
    float scale = FP8_MAX / amax;
    float recip = 1.0f / scale;

    __shared__ __bf16 sW[BN * PITCH];  // 9216 B
    __shared__ __bf16 sA[M * PITCH];   // 4608 B

    const int t = threadIdx.x;
    const int lane = t & 63;
    const int wave = t >> 6;
    const int col = lane & 15;
    const int quad = lane >> 4;

    f32x4 acc0 = {0.f, 0.f, 0.f, 0.f};
    f32x4 acc1 = {0.f, 0.f, 0.f, 0.f};

    for (int it = 0; it < NITER; ++it) {
        const int kb = kbase0 + it * BK;
        // stage W tile [64 rows x 64 k] fp32 -> quantize -> bf16 LDS
#pragma unroll
        for (int j = 0; j < 4; ++j) {
            int flat = j * 256 + t;
            int row = flat >> 4, kq = flat & 15;   // 16 float4 per row
            float4 w = *(const float4*)(W + (n0 + row) * K + kb + kq * 4);
            *(bf16x4*)&sW[row * PITCH + kq * 4] = quant4(w, scale, recip);
        }
        // stage A tile [32 rows x 64 k] fp32 -> bf16 LDS
#pragma unroll
        for (int j = 0; j < 2; ++j) {
            int flat = j * 256 + t;
            int row = flat >> 4, kq = flat & 15;
            float4 a = *(const float4*)(A + row * K + kb + kq * 4);
            bf16x4 pa;
            pa.x = (__bf16)a.x; pa.y = (__bf16)a.y;
            pa.z = (__bf16)a.z; pa.w = (__bf16)a.w;
            *(bf16x4*)&sA[row * PITCH + kq * 4] = pa;
        }
        __syncthreads();
#pragma unroll
        for (int s = 0; s < 2; ++s) {
            int kk = s * 32 + quad * 8;
            bf16x8 bfrag = *(bf16x8*)&sW[(wave * 16 + col) * PITCH + kk];
            bf16x8 a0 = *(bf16x8*)&sA[col * PITCH + kk];
            bf16x8 a1 = *(bf16x8*)&sA[(16 + col) * PITCH + kk];
            acc0 = __builtin_amdgcn_mfma_f32_16x16x32_bf16(a0, bfrag, acc0, 0, 0, 0);
            acc1 = __builtin_amdgcn_mfma_f32_16x16x32_bf16(a1, bfrag, acc1, 0, 0, 0);
        }
        __syncthreads();
    }

    // epilogue: C/D layout col=lane&15, row=quad*4+reg; atomicAdd partials.
    const int gn = n0 + wave * 16 + col;
    const float b = (blockIdx.y == 0) ? bias[gn] : 0.0f;
#pragma unroll
    for (int r = 0; r < 4; ++r) {
        int m0 = quad * 4 + r;
        atomicAdd(&C[m0 * N + gn], acc0[r] + b);
        atomicAdd(&C[(16 + m0) * N + gn], acc1[r] + b);
    }
}

extern "C" void kernel_launch(void* const* d_in, const int* in_sizes, int n_in,
                              void* d_out, int out_size, void* d_ws, size_t ws_size,
                              hipStream_t stream) {
    const float* A    = (const float*)d_in[0];
    const float* W    = (const float*)d_in[1];
    const float* bias = (const float*)d_in[2];
    float* C = (float*)d_out;
    unsigned int* amax_bits = (unsigned int*)d_ws;

    hipMemsetAsync(d_ws, 0, 4, stream);
    hipMemsetAsync(d_out, 0, (size_t)M * N * sizeof(float), stream);

    amax_kernel<<<2048, 256, 0, stream>>>((const float4*)W, amax_bits);

    dim3 grid(N / BN, KSPLIT);
    fused_gemm<<<grid, 256, 0, stream>>>(A, W, bias, amax_bits, C);
}

// Round 2
// 320.315 us; speedup vs baseline: 1.0307x; 1.0307x over previous
//
#include <hip/hip_runtime.h>
#include <hip/hip_bf16.h>

typedef __bf16 bf16x8 __attribute__((ext_vector_type(8)));
typedef __bf16 bf16x4 __attribute__((ext_vector_type(4)));
typedef float  f32x4  __attribute__((ext_vector_type(4)));
typedef float  f32x2  __attribute__((ext_vector_type(2)));

#define FP8_MAX 448.0f
#define M 32
#define N 12288
#define K 4096

// ---------------- Pass 1: global amax over |W|, fused with A bf16 pre-swizzle ----
// A_sw layout: fragment slot (s, mt, lane) at element ((s*2+mt)*64 + lane)*8 holds
//   A[mt*16 + (lane&15)][s*32 + (lane>>4)*8 + j], j=0..7  (exact MFMA A-frag order)
__global__ __launch_bounds__(256) void amax_pack(const float4* __restrict__ W4,
                                                 const float* __restrict__ A,
                                                 unsigned int* __restrict__ amax_bits,
                                                 __bf16* __restrict__ A_sw) {
    // A-pack: blocks 0..63 (16384 threads, one 8-elem fragment slot each)
    if (blockIdx.x < 64) {
        int tid  = blockIdx.x * 256 + threadIdx.x;   // 0..16383
        int lane = tid & 63;
        int mt   = (tid >> 6) & 1;
        int s    = tid >> 7;                         // 0..127
        int row  = mt * 16 + (lane & 15);
        int kk   = s * 32 + (lane >> 4) * 8;
        const float* src = A + row * K + kk;
        f32x4 a0 = *(const f32x4*)src;
        f32x4 a1 = *(const f32x4*)(src + 4);
        bf16x8 p;
        p[0] = (__bf16)a0[0]; p[1] = (__bf16)a0[1];
        p[2] = (__bf16)a0[2]; p[3] = (__bf16)a0[3];
        p[4] = (__bf16)a1[0]; p[5] = (__bf16)a1[1];
        p[6] = (__bf16)a1[2]; p[7] = (__bf16)a1[3];
        *(bf16x8*)(A_sw + (size_t)tid * 8) = p;
    }
    // amax over W
    const int n4 = (N * K) / 4;                      // 12582912 float4
    int idx = blockIdx.x * 256 + threadIdx.x;
    int stride = gridDim.x * 256;                    // 524288 -> 24 iters/thread
    float m = 0.0f;
    for (int i = idx; i < n4; i += stride) {
        float4 v = W4[i];
        m = fmaxf(m, fabsf(v.x)); m = fmaxf(m, fabsf(v.y));
        m = fmaxf(m, fabsf(v.z)); m = fmaxf(m, fabsf(v.w));
    }
#pragma unroll
    for (int off = 32; off > 0; off >>= 1)
        m = fmaxf(m, __shfl_down(m, off, 64));
    __shared__ float smax[4];
    if ((threadIdx.x & 63) == 0) smax[threadIdx.x >> 6] = m;
    __syncthreads();
    if (threadIdx.x == 0) {
        float bm = fmaxf(fmaxf(smax[0], smax[1]), fmaxf(smax[2], smax[3]));
        atomicMax(amax_bits, __float_as_uint(bm));   // vals >=0: uint order == float order
    }
}

// quantize 4 fp32 weights -> fp8 e4m3fn (HW RNE) -> dequant -> bf16
__device__ inline bf16x4 quant4(const f32x4 w, float scale, float recip) {
    float x0 = fminf(fmaxf(w[0] * scale, -FP8_MAX), FP8_MAX);
    float x1 = fminf(fmaxf(w[1] * scale, -FP8_MAX), FP8_MAX);
    float x2 = fminf(fmaxf(w[2] * scale, -FP8_MAX), FP8_MAX);
    float x3 = fminf(fmaxf(w[3] * scale, -FP8_MAX), FP8_MAX);
    int p01 = __builtin_amdgcn_cvt_pk_fp8_f32(x0, x1, 0, false);
    int p23 = __builtin_amdgcn_cvt_pk_fp8_f32(x2, x3, 0, false);
    f32x2 d01 = __builtin_amdgcn_cvt_pk_f32_fp8(p01, false);
    f32x2 d23 = __builtin_amdgcn_cvt_pk_f32_fp8(p23, false);
    bf16x4 r;
    r[0] = (__bf16)(d01.x * recip);
    r[1] = (__bf16)(d01.y * recip);
    r[2] = (__bf16)(d23.x * recip);
    r[3] = (__bf16)(d23.y * recip);
    return r;
}

// ---------------- Pass 2: barrier-free streamed quantize + GEMM ----------------
// grid: N/16 = 768 single-wave blocks (3 waves/CU). Wave owns 16 output cols,
// full K, both 16-row m-tiles. W: global->VGPR->quant->MFMA, no LDS, no barriers.
__global__ __launch_bounds__(64) void fused_gemm(const float* __restrict__ W,
                                                 const __bf16* __restrict__ A_sw,
                                                 const float* __restrict__ bias,
                                                 const unsigned int* __restrict__ amax_bits,
                                                 float* __restrict__ C) {
    const int n0 = blockIdx.x * 16;
    const int lane = threadIdx.x;
    const int col = lane & 15;
    const int quad = lane >> 4;

    float amax  = fmaxf(__uint_as_float(*amax_bits), 1e-12f);
    float scale = FP8_MAX / amax;
    float recip = 1.0f / scale;

    const float*  wrow = W + (size_t)(n0 + col) * K + quad * 8;  // B-frag base
    const __bf16* ap   = A_sw + (size_t)lane * 8;                // A-frag base

    f32x4 acc0 = {0.f, 0.f, 0.f, 0.f};
    f32x4 acc1 = {0.f, 0.f, 0.f, 0.f};

#pragma unroll 4
    for (int s = 0; s < K / 32; ++s) {
        f32x4 w0 = *(const f32x4*)(wrow + s * 32);
        f32x4 w1 = *(const f32x4*)(wrow + s * 32 + 4);
        union { bf16x8 v; bf16x4 h[2]; } b;
        b.h[0] = quant4(w0, scale, recip);
        b.h[1] = quant4(w1, scale, recip);
        bf16x8 a0 = *(const bf16x8*)(ap + s * 1024);        // slot (s, mt=0)
        bf16x8 a1 = *(const bf16x8*)(ap + s * 1024 + 512);  // slot (s, mt=1)
        acc0 = __builtin_amdgcn_mfma_f32_16x16x32_bf16(a0, b.v, acc0, 0, 0, 0);
        acc1 = __builtin_amdgcn_mfma_f32_16x16x32_bf16(a1, b.v, acc1, 0, 0, 0);
    }

    // C/D layout: col=lane&15, row=quad*4+r (validated round 1)
    const int gn = n0 + col;
    const float bv = bias[gn];
#pragma unroll
    for (int r = 0; r < 4; ++r) {
        C[(quad * 4 + r) * N + gn]        = acc0[r] + bv;
        C[(16 + quad * 4 + r) * N + gn]   = acc1[r] + bv;
    }
}

extern "C" void kernel_launch(void* const* d_in, const int* in_sizes, int n_in,
                              void* d_out, int out_size, void* d_ws, size_t ws_size,
                              hipStream_t stream) {
    const float* A    = (const float*)d_in[0];
    const float* W    = (const float*)d_in[1];
    const float* bias = (const float*)d_in[2];
    float* C = (float*)d_out;
    unsigned int* amax_bits = (unsigned int*)d_ws;
    __bf16* A_sw = (__bf16*)((char*)d_ws + 4096);   // 256 KB, rewritten every launch

    hipMemsetAsync(d_ws, 0, 4, stream);             // amax_bits = 0

    amax_pack<<<2048, 256, 0, stream>>>((const float4*)W, A, amax_bits, A_sw);

    fused_gemm<<<N / 16, 64, 0, stream>>>(W, A_sw, bias, amax_bits, C);
}

// Round 3
// 305.959 us; speedup vs baseline: 1.0791x; 1.0469x over previous
//
#include <hip/hip_runtime.h>
#include <hip/hip_bf16.h>

typedef __bf16 bf16x8 __attribute__((ext_vector_type(8)));
typedef __bf16 bf16x4 __attribute__((ext_vector_type(4)));
typedef float  f32x4  __attribute__((ext_vector_type(4)));
typedef float  f32x2  __attribute__((ext_vector_type(2)));

#define FP8_MAX 448.0f
#define M 32
#define N 12288
#define K 4096
#define NBLK 2048   // amax_pack grid size == slot count

// ---------------- Pass 1: per-block amax over |W| + A bf16 pre-swizzle ----------
// slots[blockIdx.x] <- block max (plain store, no init needed: every slot is
// written unconditionally every launch, read only by the later gemm dispatch).
// A_sw layout: fragment slot (s, mt, lane) at element ((s*2+mt)*64 + lane)*8 holds
//   A[mt*16 + (lane&15)][s*32 + (lane>>4)*8 + j], j=0..7  (exact MFMA A-frag order)
__global__ __launch_bounds__(256) void amax_pack(const float4* __restrict__ W4,
                                                 const float* __restrict__ A,
                                                 float* __restrict__ slots,
                                                 __bf16* __restrict__ A_sw) {
    // A-pack: blocks 0..63 (16384 threads, one 8-elem fragment slot each)
    if (blockIdx.x < 64) {
        int tid  = blockIdx.x * 256 + threadIdx.x;   // 0..16383
        int lane = tid & 63;
        int mt   = (tid >> 6) & 1;
        int s    = tid >> 7;                         // 0..127
        int row  = mt * 16 + (lane & 15);
        int kk   = s * 32 + (lane >> 4) * 8;
        const float* src = A + row * K + kk;
        f32x4 a0 = *(const f32x4*)src;
        f32x4 a1 = *(const f32x4*)(src + 4);
        bf16x8 p;
        p[0] = (__bf16)a0[0]; p[1] = (__bf16)a0[1];
        p[2] = (__bf16)a0[2]; p[3] = (__bf16)a0[3];
        p[4] = (__bf16)a1[0]; p[5] = (__bf16)a1[1];
        p[6] = (__bf16)a1[2]; p[7] = (__bf16)a1[3];
        *(bf16x8*)(A_sw + (size_t)tid * 8) = p;
    }
    // amax over W (grid-stride, 24 float4/thread)
    const int n4 = (N * K) / 4;                      // 12582912 float4
    int idx = blockIdx.x * 256 + threadIdx.x;
    int stride = gridDim.x * 256;
    float m = 0.0f;
    for (int i = idx; i < n4; i += stride) {
        float4 v = W4[i];
        m = fmaxf(m, fabsf(v.x)); m = fmaxf(m, fabsf(v.y));
        m = fmaxf(m, fabsf(v.z)); m = fmaxf(m, fabsf(v.w));
    }
#pragma unroll
    for (int off = 32; off > 0; off >>= 1)
        m = fmaxf(m, __shfl_down(m, off, 64));
    __shared__ float smax[4];
    if ((threadIdx.x & 63) == 0) smax[threadIdx.x >> 6] = m;
    __syncthreads();
    if (threadIdx.x == 0)
        slots[blockIdx.x] = fmaxf(fmaxf(smax[0], smax[1]), fmaxf(smax[2], smax[3]));
}

// quantize 4 fp32 weights -> fp8 e4m3fn (HW RNE) -> dequant -> bf16
__device__ inline bf16x4 quant4(const f32x4 w, float scale, float recip) {
    float x0 = fminf(fmaxf(w[0] * scale, -FP8_MAX), FP8_MAX);
    float x1 = fminf(fmaxf(w[1] * scale, -FP8_MAX), FP8_MAX);
    float x2 = fminf(fmaxf(w[2] * scale, -FP8_MAX), FP8_MAX);
    float x3 = fminf(fmaxf(w[3] * scale, -FP8_MAX), FP8_MAX);
    int p01 = __builtin_amdgcn_cvt_pk_fp8_f32(x0, x1, 0, false);
    int p23 = __builtin_amdgcn_cvt_pk_fp8_f32(x2, x3, 0, false);
    f32x2 d01 = __builtin_amdgcn_cvt_pk_f32_fp8(p01, false);
    f32x2 d23 = __builtin_amdgcn_cvt_pk_f32_fp8(p23, false);
    bf16x4 r;
    r[0] = (__bf16)(d01.x * recip);
    r[1] = (__bf16)(d01.y * recip);
    r[2] = (__bf16)(d23.x * recip);
    r[3] = (__bf16)(d23.y * recip);
    return r;
}

// ---------------- Pass 2: barrier-free streamed quantize + GEMM ----------------
// grid: N/16 = 768 single-wave blocks. Wave owns 16 output cols, full K, both
// 16-row m-tiles. W: global->VGPR->quant->MFMA, no LDS, no barriers.
// Prologue: reduce the 2048 amax slots (L2-resident, ~0.5 us, overlaps W prefetch).
__global__ __launch_bounds__(64) void fused_gemm(const float* __restrict__ W,
                                                 const __bf16* __restrict__ A_sw,
                                                 const float* __restrict__ bias,
                                                 const float* __restrict__ slots,
                                                 float* __restrict__ C) {
    const int n0 = blockIdx.x * 16;
    const int lane = threadIdx.x;
    const int col = lane & 15;
    const int quad = lane >> 4;

    // reduce 2048 slot maxima -> global amax (all lanes end with the value)
    const f32x4* sl4 = (const f32x4*)slots;          // 512 float4
    float m = 0.0f;
#pragma unroll
    for (int i = 0; i < 8; ++i) {
        f32x4 v = sl4[lane + i * 64];
        m = fmaxf(fmaxf(m, fmaxf(v[0], v[1])), fmaxf(v[2], v[3]));
    }
#pragma unroll
    for (int off = 32; off > 0; off >>= 1)
        m = fmaxf(m, __shfl_xor(m, off, 64));
    float amax  = fmaxf(m, 1e-12f);
    float scale = FP8_MAX / amax;
    float recip = 1.0f / scale;

    const float*  wrow = W + (size_t)(n0 + col) * K + quad * 8;  // B-frag base
    const __bf16* ap   = A_sw + (size_t)lane * 8;                // A-frag base
    const float bv = bias[n0 + col];

    f32x4 acc0 = {0.f, 0.f, 0.f, 0.f};
    f32x4 acc1 = {0.f, 0.f, 0.f, 0.f};

#pragma unroll 4
    for (int s = 0; s < K / 32; ++s) {
        f32x4 w0 = *(const f32x4*)(wrow + s * 32);
        f32x4 w1 = *(const f32x4*)(wrow + s * 32 + 4);
        union { bf16x8 v; bf16x4 h[2]; } b;
        b.h[0] = quant4(w0, scale, recip);
        b.h[1] = quant4(w1, scale, recip);
        bf16x8 a0 = *(const bf16x8*)(ap + s * 1024);        // slot (s, mt=0)
        bf16x8 a1 = *(const bf16x8*)(ap + s * 1024 + 512);  // slot (s, mt=1)
        acc0 = __builtin_amdgcn_mfma_f32_16x16x32_bf16(a0, b.v, acc0, 0, 0, 0);
        acc1 = __builtin_amdgcn_mfma_f32_16x16x32_bf16(a1, b.v, acc1, 0, 0, 0);
    }

    // C/D layout: col=lane&15, row=quad*4+r (validated round 1)
    const int gn = n0 + col;
#pragma unroll
    for (int r = 0; r < 4; ++r) {
        C[(quad * 4 + r) * N + gn]      = acc0[r] + bv;
        C[(16 + quad * 4 + r) * N + gn] = acc1[r] + bv;
    }
}

extern "C" void kernel_launch(void* const* d_in, const int* in_sizes, int n_in,
                              void* d_out, int out_size, void* d_ws, size_t ws_size,
                              hipStream_t stream) {
    const float* A    = (const float*)d_in[0];
    const float* W    = (const float*)d_in[1];
    const float* bias = (const float*)d_in[2];
    float* C = (float*)d_out;
    float*  slots = (float*)d_ws;                    // 2048 floats (8 KB)
    __bf16* A_sw  = (__bf16*)((char*)d_ws + 8192);   // 256 KB, rewritten every launch

    amax_pack<<<NBLK, 256, 0, stream>>>((const float4*)W, A, slots, A_sw);
    fused_gemm<<<N / 16, 64, 0, stream>>>(W, A_sw, bias, slots, C);
}

// Round 4
// 304.762 us; speedup vs baseline: 1.0833x; 1.0039x over previous
//
#include <hip/hip_runtime.h>
#include <hip/hip_bf16.h>

typedef __bf16 bf16x8 __attribute__((ext_vector_type(8)));
typedef __bf16 bf16x4 __attribute__((ext_vector_type(4)));
typedef float  f32x4  __attribute__((ext_vector_type(4)));
typedef float  f32x2  __attribute__((ext_vector_type(2)));

#define FP8_MAX 448.0f
#define M 32
#define N 12288
#define K 4096
#define NBLK 2048   // amax_pack grid size == slot count

// ---------------- Pass 1: per-block amax over |W| + A bf16 pre-swizzle ----------
// slots[blockIdx.x] <- block max (plain store, no init needed: written
// unconditionally every launch, read only by the later gemm dispatch).
// A_sw layout: fragment slot (s, mt, lane) at element ((s*2+mt)*64 + lane)*8 holds
//   A[mt*16 + (lane&15)][s*32 + (lane>>4)*8 + j], j=0..7  (exact MFMA A-frag order)
__global__ __launch_bounds__(256) void amax_pack(const float4* __restrict__ W4,
                                                 const float* __restrict__ A,
                                                 float* __restrict__ slots,
                                                 __bf16* __restrict__ A_sw) {
    if (blockIdx.x < 64) {
        int tid  = blockIdx.x * 256 + threadIdx.x;   // 0..16383
        int lane = tid & 63;
        int mt   = (tid >> 6) & 1;
        int s    = tid >> 7;                         // 0..127
        int row  = mt * 16 + (lane & 15);
        int kk   = s * 32 + (lane >> 4) * 8;
        const float* src = A + row * K + kk;
        f32x4 a0 = *(const f32x4*)src;
        f32x4 a1 = *(const f32x4*)(src + 4);
        bf16x8 p;
        p[0] = (__bf16)a0[0]; p[1] = (__bf16)a0[1];
        p[2] = (__bf16)a0[2]; p[3] = (__bf16)a0[3];
        p[4] = (__bf16)a1[0]; p[5] = (__bf16)a1[1];
        p[6] = (__bf16)a1[2]; p[7] = (__bf16)a1[3];
        *(bf16x8*)(A_sw + (size_t)tid * 8) = p;
    }
    const int n4 = (N * K) / 4;                      // 12582912 float4
    int idx = blockIdx.x * 256 + threadIdx.x;
    int stride = gridDim.x * 256;
    float m = 0.0f;
    for (int i = idx; i < n4; i += stride) {
        float4 v = W4[i];
        m = fmaxf(m, fabsf(v.x)); m = fmaxf(m, fabsf(v.y));
        m = fmaxf(m, fabsf(v.z)); m = fmaxf(m, fabsf(v.w));
    }
#pragma unroll
    for (int off = 32; off > 0; off >>= 1)
        m = fmaxf(m, __shfl_down(m, off, 64));
    __shared__ float smax[4];
    if ((threadIdx.x & 63) == 0) smax[threadIdx.x >> 6] = m;
    __syncthreads();
    if (threadIdx.x == 0)
        slots[blockIdx.x] = fmaxf(fmaxf(smax[0], smax[1]), fmaxf(smax[2], smax[3]));
}

// quantize 4 fp32 weights -> fp8 e4m3fn (HW RNE) -> dequant -> bf16
__device__ inline bf16x4 quant4(const f32x4 w, float scale, float recip) {
    float x0 = fminf(fmaxf(w[0] * scale, -FP8_MAX), FP8_MAX);
    float x1 = fminf(fmaxf(w[1] * scale, -FP8_MAX), FP8_MAX);
    float x2 = fminf(fmaxf(w[2] * scale, -FP8_MAX), FP8_MAX);
    float x3 = fminf(fmaxf(w[3] * scale, -FP8_MAX), FP8_MAX);
    int p01 = __builtin_amdgcn_cvt_pk_fp8_f32(x0, x1, 0, false);
    int p23 = __builtin_amdgcn_cvt_pk_fp8_f32(x2, x3, 0, false);
    f32x2 d01 = __builtin_amdgcn_cvt_pk_f32_fp8(p01, false);
    f32x2 d23 = __builtin_amdgcn_cvt_pk_f32_fp8(p23, false);
    bf16x4 r;
    r[0] = (__bf16)(d01.x * recip);
    r[1] = (__bf16)(d01.y * recip);
    r[2] = (__bf16)(d23.x * recip);
    r[3] = (__bf16)(d23.y * recip);
    return r;
}

// ---------------- Pass 2: streamed quantize + GEMM, in-block K-split ----------
// grid: N/16 = 768 blocks x 4 waves (12 waves/CU). Block owns 16 output cols;
// wave w handles K-chunk [w*1024, (w+1)*1024). W: global->VGPR->quant->MFMA,
// no LDS staging; one barrier for the 4-way partial-sum reduction.
__global__ __launch_bounds__(256) void fused_gemm(const float* __restrict__ W,
                                                  const __bf16* __restrict__ A_sw,
                                                  const float* __restrict__ bias,
                                                  const float* __restrict__ slots,
                                                  float* __restrict__ C) {
    const int n0 = blockIdx.x * 16;
    const int t = threadIdx.x;
    const int lane = t & 63;
    const int wave = t >> 6;
    const int col = lane & 15;
    const int quad = lane >> 4;

    // reduce 2048 slot maxima -> global amax (every wave computes it)
    const f32x4* sl4 = (const f32x4*)slots;          // 512 float4
    float m = 0.0f;
#pragma unroll
    for (int i = 0; i < 8; ++i) {
        f32x4 v = sl4[lane + i * 64];
        m = fmaxf(fmaxf(m, fmaxf(v[0], v[1])), fmaxf(v[2], v[3]));
    }
#pragma unroll
    for (int off = 32; off > 0; off >>= 1)
        m = fmaxf(m, __shfl_xor(m, off, 64));
    float amax  = fmaxf(m, 1e-12f);
    float scale = FP8_MAX / amax;
    float recip = 1.0f / scale;

    const float*  wrow = W + (size_t)(n0 + col) * K + quad * 8;  // B-frag base
    const __bf16* ap   = A_sw + (size_t)lane * 8;                // A-frag base

    f32x4 acc0 = {0.f, 0.f, 0.f, 0.f};
    f32x4 acc1 = {0.f, 0.f, 0.f, 0.f};

    const int s0 = wave * (K / 32 / 4);              // 32 s-iters per wave
#pragma unroll 4
    for (int si = 0; si < K / 32 / 4; ++si) {
        const int s = s0 + si;
        f32x4 w0 = *(const f32x4*)(wrow + s * 32);
        f32x4 w1 = *(const f32x4*)(wrow + s * 32 + 4);
        union { bf16x8 v; bf16x4 h[2]; } b;
        b.h[0] = quant4(w0, scale, recip);
        b.h[1] = quant4(w1, scale, recip);
        bf16x8 a0 = *(const bf16x8*)(ap + s * 1024);        // slot (s, mt=0)
        bf16x8 a1 = *(const bf16x8*)(ap + s * 1024 + 512);  // slot (s, mt=1)
        acc0 = __builtin_amdgcn_mfma_f32_16x16x32_bf16(a0, b.v, acc0, 0, 0, 0);
        acc1 = __builtin_amdgcn_mfma_f32_16x16x32_bf16(a1, b.v, acc1, 0, 0, 0);
    }

    // 4-way partial reduction: waves 1..3 park partials in LDS; wave 0 sums.
    __shared__ float red[3][64][8];                  // 6 KB
    if (wave != 0) {
        float* dst = &red[wave - 1][lane][0];
#pragma unroll
        for (int r = 0; r < 4; ++r) { dst[r] = acc0[r]; dst[4 + r] = acc1[r]; }
    }
    __syncthreads();
    if (wave == 0) {
        const int gn = n0 + col;
        const float bv = bias[gn];
#pragma unroll
        for (int r = 0; r < 4; ++r) {
            float v0 = acc0[r] + red[0][lane][r]     + red[1][lane][r]     + red[2][lane][r];
            float v1 = acc1[r] + red[0][lane][4 + r] + red[1][lane][4 + r] + red[2][lane][4 + r];
            // C/D layout: col=lane&15, row=quad*4+r (validated round 1)
            C[(quad * 4 + r) * N + gn]      = v0 + bv;
            C[(16 + quad * 4 + r) * N + gn] = v1 + bv;
        }
    }
}

extern "C" void kernel_launch(void* const* d_in, const int* in_sizes, int n_in,
                              void* d_out, int out_size, void* d_ws, size_t ws_size,
                              hipStream_t stream) {
    const float* A    = (const float*)d_in[0];
    const float* W    = (const float*)d_in[1];
    const float* bias = (const float*)d_in[2];
    float* C = (float*)d_out;
    float*  slots = (float*)d_ws;                    // 2048 floats (8 KB)
    __bf16* A_sw  = (__bf16*)((char*)d_ws + 8192);   // 256 KB, rewritten every launch

    amax_pack<<<NBLK, 256, 0, stream>>>((const float4*)W, A, slots, A_sw);
    fused_gemm<<<N / 16, 256, 0, stream>>>(W, A_sw, bias, slots, C);
}